// Round 11
// baseline (444.591 us; speedup 1.0000x reference)
//
#include <hip/hip_runtime.h>
#include <hip/hip_fp16.h>

// Problem constants (from reference setup_inputs)
#define N_TOK 65536
#define KNB 32
#define DIM 128
#define BETA 0.5f
// RHO == 1.0f folded into the arithmetic.

typedef _Float16 h2 __attribute__((ext_vector_type(2)));

// cvt_pkrtz returns __fp16x2; bit-identical to h2, clang wants a cast.
static __device__ __forceinline__ h2 pkrtz(float a, float b) {
    return __builtin_bit_cast(h2, __builtin_amdgcn_cvt_pkrtz(a, b));
}

// ---- fused pre-pass ----
// blocks [0,8192): M fp32 -> fp16 pairs (2.1M float4s)
// blocks [8192,10240): P fp32 -> DUPLICATED fp16 pairs (pk,pk) for v_pk_fma
__global__ __launch_bounds__(256) void convert_inputs(
    const float4* __restrict__ M4, h2* __restrict__ M16,
    const float4* __restrict__ P4, h2* __restrict__ P2)
{
    const int b = blockIdx.x;
    if (b < 8192) {
        const int i = b * 256 + threadIdx.x;          // < 2,097,152
        const float4 f = M4[i];
        M16[2 * i]     = pkrtz(f.x, f.y);
        M16[2 * i + 1] = pkrtz(f.z, f.w);
    } else {
        const int i = (b - 8192) * 256 + threadIdx.x; // < 524,288
        const float4 f = P4[i];
        P2[4 * i + 0] = pkrtz(f.x, f.x);
        P2[4 * i + 1] = pkrtz(f.y, f.y);
        P2[4 * i + 2] = pkrtz(f.z, f.z);
        P2[4 * i + 3] = pkrtz(f.w, f.w);
    }
}

// M-only convert (fallback when ws can't hold P2)
__global__ __launch_bounds__(256) void convert_m(
    const float4* __restrict__ M4, h2* __restrict__ M16, int n4)
{
    const int i = blockIdx.x * 256 + threadIdx.x;
    if (i < n4) {
        const float4 f = M4[i];
        M16[2 * i]     = pkrtz(f.x, f.y);
        M16[2 * i + 1] = pkrtz(f.z, f.w);
    }
}

// ONE wave per row; lane owns dims (2*lane,2*lane+1) as ONE packed h2.
// t[32] h2 = 32 VGPRs (no AGPR parking, no cvt): gather loop is
// load + v_pk_fma_f16; scores are v_dot2_f32_f16. Warm replays proved the
// kernel is VALU+latency bound (r9: warm 42MB HBM, same 108us), so this
// targets issued-ops/wave, not bytes.
template<int HAS_P2>
__global__ __launch_bounds__(256, 4) void mirror_main(
    const h2*    __restrict__ M16,
    const h2*    __restrict__ P2,
    const float* __restrict__ P,
    const float* __restrict__ Y,
    const float* __restrict__ Lam,
    const int*   __restrict__ Kset,
    float* __restrict__ Pnew,
    float* __restrict__ LamNew,
    float* __restrict__ blockPartials)
{
    const int wid  = threadIdx.x >> 6;     // wave id in block (0..3)
    const int lane = threadIdx.x & 63;
    const int n    = blockIdx.x * 4 + wid; // row index
    const int d0   = lane * 2;

    const float2 y   = *(const float2*)&Y[n * DIM + d0];
    const float2 lam = *(const float2*)&Lam[n * DIM + d0];

    const int*   ks    = &Kset[n * KNB];   // wave-uniform -> s_load
    const float* prow  = &P[n * KNB];      // wave-uniform -> s_load
    const h2*    p2row = &P2[n * KNB];     // wave-uniform -> s_load

    // ---- gather + Y_from_P in packed fp16 (1 pk_fma per k) ----
    h2 t[KNB];
    h2 yph; yph.x = yph.y = (_Float16)0;
    #pragma unroll
    for (int k = 0; k < KNB; ++k) {
        const int idx = ks[k];
        t[k] = M16[(size_t)idx * (DIM / 2) + lane];
        asm("" : "+v"(t[k]));              // keep resident, no re-gather
        h2 pk2;
        if (HAS_P2) {
            pk2 = p2row[k];
        } else {
            const float pk = prow[k];
            pk2 = pkrtz(pk, pk);
        }
        yph += t[k] * pk2;                 // v_pk_fma_f16
    }
    const float ypx = (float)yph.x;
    const float ypy = (float)yph.y;

    // xi = lam + rho*(y - yp)   (RHO = 1)
    const float xix = lam.x + (y.x - ypx);
    const float xiy = lam.y + (y.y - ypy);
    const h2 xi2 = pkrtz(xix, xiy);

    // ---- per-lane score partials: 1 fdot2 per k (fp32 accumulate) ----
    float v[KNB];
    #pragma unroll
    for (int k = 0; k < KNB; ++k)
        v[k] = __builtin_amdgcn_fdot2(t[k], xi2, 0.f, false);

    // ---- reduce-scatter: 32 shuffles; lane l ends with full score k=(l>>1)
    #pragma unroll
    for (int dd = 32; dd >= 2; dd >>= 1) {
        const int hw = dd >> 1;
        const bool upper = (lane & dd) != 0;
        #pragma unroll
        for (int j = 0; j < hw; ++j) {
            const float send = upper ? v[j] : v[j + hw];
            const float keep = upper ? v[j + hw] : v[j];
            const float recv = __shfl_xor(send, dd, 64);
            v[j] = keep + recv;
        }
    }
    const float S = v[0] + __shfl_xor(v[0], 1, 64);
    const int myk = lane >> 1;

    // ---- distributed softmax: softmax(log P - beta*S)
    //      == P*exp(-beta*(S-m))/sum; k lives on lane pairs (dist 2..32).
    float m = S;
    #pragma unroll
    for (int dd = 2; dd <= 32; dd <<= 1)
        m = fminf(m, __shfl_xor(m, dd, 64));

    const float pk_mine = prow[myk];       // fp32 P for softmax accuracy
    float e = pk_mine * __expf(-BETA * (S - m));
    float esum = e;
    #pragma unroll
    for (int dd = 2; dd <= 32; dd <<= 1)
        esum += __shfl_xor(esum, dd, 64);

    const float inv = 1.f / esum;
    const float pn_mine = e * inv;

    // compact k -> lanes 0..31, one coalesced 128 B store
    const float pn_compact = __shfl(pn_mine, lane * 2, 64);
    if (lane < KNB)
        Pnew[n * KNB + lane] = pn_compact;

    // ---- pass 2: Y_from_Pnew. readlane -> cvt_pkrtz -> pk_fma per k. ----
    h2 yp2h; yp2h.x = yp2h.y = (_Float16)0;
    #pragma unroll
    for (int k = 0; k < KNB; ++k) {
        const float pn = __uint_as_float(
            __builtin_amdgcn_readlane(__float_as_uint(pn_mine), 2 * k));
        const h2 pn2 = pkrtz(pn, pn);
        yp2h += t[k] * pn2;                // v_pk_fma_f16
    }
    const float yp2x = (float)yp2h.x;
    const float yp2y = (float)yp2h.y;

    const float rx = y.x - yp2x;
    const float ry = y.y - yp2y;
    const float lnx = lam.x + rx;          // RHO = 1
    const float lny = lam.y + ry;
    *(float2*)&LamNew[n * DIM + d0] = make_float2(lnx, lny);

    // energy: 0.5*r^2 + ln*r over this lane's 2 dims; wave then block sum.
    float c = 0.5f * (rx * rx + ry * ry) + lnx * rx + lny * ry;
    #pragma unroll
    for (int dd = 1; dd <= 32; dd <<= 1)
        c += __shfl_xor(c, dd, 64);

    __shared__ float wsum[4];
    if (lane == 0) wsum[wid] = c;
    __syncthreads();
    if (threadIdx.x == 0)
        blockPartials[blockIdx.x] = wsum[0] + wsum[1] + wsum[2] + wsum[3];
}

// Single-kernel deterministic reduction of 16384 partials.
__global__ __launch_bounds__(256) void reduce_energy(
    const float4* __restrict__ in, float* __restrict__ out)
{
    float acc = 0.f;
    #pragma unroll
    for (int i = 0; i < 16; ++i) {
        const float4 f = in[threadIdx.x + 256 * i];
        acc += (f.x + f.y) + (f.z + f.w);
    }
    __shared__ float s[256];
    s[threadIdx.x] = acc;
    __syncthreads();
    for (int sft = 128; sft > 0; sft >>= 1) {
        if (threadIdx.x < sft) s[threadIdx.x] += s[threadIdx.x + sft];
        __syncthreads();
    }
    if (threadIdx.x == 0) out[0] = s[0];
}

extern "C" void kernel_launch(void* const* d_in, const int* in_sizes, int n_in,
                              void* d_out, int out_size, void* d_ws, size_t ws_size,
                              hipStream_t stream) {
    // inputs in setup_inputs() dict order: M, P, Y, Lam, Kset
    const float* M    = (const float*)d_in[0];
    const float* P    = (const float*)d_in[1];
    const float* Y    = (const float*)d_in[2];
    const float* Lam  = (const float*)d_in[3];
    const int*   Kset = (const int*)d_in[4];

    float* out    = (float*)d_out;
    float* Pnew   = out;                               // N*K floats
    float* LamNew = out + (size_t)N_TOK * KNB;         // N*D floats
    float* energy = out + (size_t)N_TOK * KNB + (size_t)N_TOK * DIM; // 1 float

    const int nBlocks = N_TOK / 4;                     // 16384 (4 rows/block)
    const size_t m16Bytes = (size_t)N_TOK * DIM * 2;   // 16.78 MB
    const size_t p2Bytes  = (size_t)N_TOK * KNB * 4;   // 8.39 MB
    const size_t partBytes = (size_t)nBlocks * 4;

    h2* M16 = (h2*)d_ws;
    if (ws_size >= m16Bytes + p2Bytes + partBytes) {
        h2* P2 = (h2*)((char*)d_ws + m16Bytes);
        float* blockPartials = (float*)((char*)d_ws + m16Bytes + p2Bytes);

        convert_inputs<<<10240, 256, 0, stream>>>(
            (const float4*)M, M16, (const float4*)P, P2);
        mirror_main<1><<<nBlocks, 256, 0, stream>>>(
            M16, P2, P, Y, Lam, Kset, Pnew, LamNew, blockPartials);
        reduce_energy<<<1, 256, 0, stream>>>(
            (const float4*)blockPartials, energy);
    } else {
        float* blockPartials = (float*)((char*)d_ws + m16Bytes);
        const int n4 = N_TOK * DIM / 4;
        convert_m<<<(n4 + 255) / 256, 256, 0, stream>>>(
            (const float4*)M, M16, n4);
        mirror_main<0><<<nBlocks, 256, 0, stream>>>(
            M16, (const h2*)nullptr, P, Y, Lam, Kset,
            Pnew, LamNew, blockPartials);
        reduce_energy<<<1, 256, 0, stream>>>(
            (const float4*)blockPartials, energy);
    }
}